// Round 6
// baseline (185.554 us; speedup 1.0000x reference)
//
#include <hip/hip_runtime.h>
#include <math.h>

#define T_LEN 256
#define HID 10

typedef float v2f __attribute__((ext_vector_type(2)));

// ds_swizzle compile-time pattern (BitMode): src = ((lane & and) | or) ^ xor
// broadcast lane J within 16-lane half-group: PAT = (J<<5) | 0x10
// xor-butterfly by M within 32 lanes:         PAT = (M<<10) | 0x1f
template <int PAT>
__device__ __forceinline__ float swz(float v) {
    return __int_as_float(__builtin_amdgcn_ds_swizzle(__float_as_int(v), PAT));
}

// setup-only accurate softplus
__device__ __forceinline__ float softplus_f(float x) {
    return fmaxf(x, 0.0f) + log1pf(expf(-fabsf(x)));
}
__device__ __forceinline__ float samp(const float* mu, const float* rho,
                                      const float* eps, int i) {
    return mu[i] + softplus_f(rho[i]) * eps[i];
}

// sigmoid = rcp(1 + 2^(-log2e*x)) : mul, exp, add, rcp
__device__ __forceinline__ float fast_sigmoid(float x) {
    float e = __builtin_amdgcn_exp2f(-1.442695040888963f * x);
    return __builtin_amdgcn_rcpf(1.0f + e);
}
// tanh = 1 - 2*rcp(2^(2*log2e*x) + 1)
__device__ __forceinline__ float fast_tanh(float x) {
    float e = __builtin_amdgcn_exp2f(2.885390081777927f * x);
    return fmaf(-2.0f, __builtin_amdgcn_rcpf(e + 1.0f), 1.0f);
}

#define DOTJ(J, HV)                                                    \
    hh.x = hh.y = (HV);                                                \
    a01 = __builtin_elementwise_fma(hh, whh01[J], a01);                \
    a23 = __builtin_elementwise_fma(hh, whh23[J], a23);

// One element's step. h is replicated across all 16 lanes in registers
// (HA array). After computing hk, re-replicate via 10 immediate-pattern
// ds_swizzle broadcasts (no VALU overhead, no LDS memory round trip);
// their latency is covered by the other element's compute (ILP=2).
#define ELEM_STEP(HA, XV, CC, HK)                                      \
    {                                                                  \
        v2f hh;                                                        \
        hh.x = hh.y = (XV);                                            \
        v2f a01 = __builtin_elementwise_fma(hh, wih01, bb01);          \
        v2f a23 = __builtin_elementwise_fma(hh, wih23, bb23);          \
        DOTJ(0, HA[0]) DOTJ(1, HA[1]) DOTJ(2, HA[2]) DOTJ(3, HA[3])    \
        DOTJ(4, HA[4]) DOTJ(5, HA[5]) DOTJ(6, HA[6]) DOTJ(7, HA[7])    \
        DOTJ(8, HA[8]) DOTJ(9, HA[9])                                  \
        float si = fast_sigmoid(a01.x);                                \
        float sf = fast_sigmoid(a01.y);                                \
        float tg = fast_tanh(a23.x);                                   \
        float so = fast_sigmoid(a23.y);                                \
        (CC) = fmaf(sf, (CC), si * tg);                                \
        (HK) = so * fast_tanh(CC);                                     \
        HA[0] = swz<(0 << 5) | 0x10>(HK);                              \
        HA[1] = swz<(1 << 5) | 0x10>(HK);                              \
        HA[2] = swz<(2 << 5) | 0x10>(HK);                              \
        HA[3] = swz<(3 << 5) | 0x10>(HK);                              \
        HA[4] = swz<(4 << 5) | 0x10>(HK);                              \
        HA[5] = swz<(5 << 5) | 0x10>(HK);                              \
        HA[6] = swz<(6 << 5) | 0x10>(HK);                              \
        HA[7] = swz<(7 << 5) | 0x10>(HK);                              \
        HA[8] = swz<(8 << 5) | 0x10>(HK);                              \
        HA[9] = swz<(9 << 5) | 0x10>(HK);                              \
    }

// one timestep: broadcast x for both elements, run both chains
#define TSTEP(TI)                                                      \
    {                                                                  \
        float xa = swz<((TI) << 5) | 0x10>(xcA);                       \
        float xb = swz<((TI) << 5) | 0x10>(xcB);                       \
        ELEM_STEP(hA, xa, cA, hkA)                                     \
        ELEM_STEP(hB, xb, cB, hkB)                                     \
    }

__global__ __launch_bounds__(256) void bayes_lstm_kernel(
    const float* __restrict__ x,
    const float* __restrict__ w_ih_mu, const float* __restrict__ w_ih_rho,
    const float* __restrict__ w_hh_mu, const float* __restrict__ w_hh_rho,
    const float* __restrict__ b_mu,    const float* __restrict__ b_rho,
    const float* __restrict__ eps_ih,  const float* __restrict__ eps_hh,
    const float* __restrict__ eps_b,
    const float* __restrict__ lin_w,   const float* __restrict__ lin_b,
    float* __restrict__ out)
{
    const int tid  = threadIdx.x;
    const int k    = tid & 15;           // hidden unit (active: k < 10)
    const int slot = tid >> 4;           // 0..15 (4 slots per wave)
    const int bA   = (blockIdx.x * 16 + slot) * 2;
    const int bB   = bA + 1;

    // ---- sample weights as {i,f} / {g,o} column pairs (zero for k>=10) ----
    v2f whh01[HID], whh23[HID];
    v2f wih01, wih23, bb01, bb23;
    wih01.x = wih01.y = 0.f; wih23.x = wih23.y = 0.f;
    bb01.x = bb01.y = 0.f;   bb23.x = bb23.y = 0.f;
    float lw = 0.f;
#pragma unroll
    for (int j = 0; j < HID; ++j) {
        whh01[j].x = whh01[j].y = 0.f;
        whh23[j].x = whh23[j].y = 0.f;
    }
    if (k < HID) {
        const int c0 = k, c1 = HID + k, c2 = 2 * HID + k, c3 = 3 * HID + k;
        wih01.x = samp(w_ih_mu, w_ih_rho, eps_ih, c0);
        wih01.y = samp(w_ih_mu, w_ih_rho, eps_ih, c1);
        wih23.x = samp(w_ih_mu, w_ih_rho, eps_ih, c2);
        wih23.y = samp(w_ih_mu, w_ih_rho, eps_ih, c3);
        bb01.x  = samp(b_mu, b_rho, eps_b, c0);
        bb01.y  = samp(b_mu, b_rho, eps_b, c1);
        bb23.x  = samp(b_mu, b_rho, eps_b, c2);
        bb23.y  = samp(b_mu, b_rho, eps_b, c3);
#pragma unroll
        for (int j = 0; j < HID; ++j) {
            whh01[j].x = samp(w_hh_mu, w_hh_rho, eps_hh, j * 4 * HID + c0);
            whh01[j].y = samp(w_hh_mu, w_hh_rho, eps_hh, j * 4 * HID + c1);
            whh23[j].x = samp(w_hh_mu, w_hh_rho, eps_hh, j * 4 * HID + c2);
            whh23[j].y = samp(w_hh_mu, w_hh_rho, eps_hh, j * 4 * HID + c3);
        }
        lw = lin_w[k];
    }

    // ---- recurrence state: replicated h in registers, no LDS ----
    float hA[HID], hB[HID];
#pragma unroll
    for (int j = 0; j < HID; ++j) { hA[j] = 0.f; hB[j] = 0.f; }
    float cA = 0.f, cB = 0.f, hkA = 0.f, hkB = 0.f;

    const float* xrA = x + (size_t)bA * T_LEN;
    const float* xrB = x + (size_t)bB * T_LEN;
    float xcA = xrA[k];                  // chunk 0: lane k holds x[t=k]
    float xcB = xrB[k];

    for (int to = 0; to < 16; ++to) {
        float xnA = 0.f, xnB = 0.f;
        if (to < 15) {                   // prefetch next 16-step chunk
            xnA = xrA[(to + 1) * 16 + k];
            xnB = xrB[(to + 1) * 16 + k];
        }
        TSTEP(0)  TSTEP(1)  TSTEP(2)  TSTEP(3)
        TSTEP(4)  TSTEP(5)  TSTEP(6)  TSTEP(7)
        TSTEP(8)  TSTEP(9)  TSTEP(10) TSTEP(11)
        TSTEP(12) TSTEP(13) TSTEP(14) TSTEP(15)
        xcA = xnA; xcB = xnB;
    }

    // ---- linear head: lane k holds final h[k]; xor-swizzle reduce ----
    float pa = hkA * lw;                 // lanes >= 10 contribute 0
    float pb = hkB * lw;
    pa += swz<(1 << 10) | 0x1f>(pa);  pb += swz<(1 << 10) | 0x1f>(pb);
    pa += swz<(2 << 10) | 0x1f>(pa);  pb += swz<(2 << 10) | 0x1f>(pb);
    pa += swz<(4 << 10) | 0x1f>(pa);  pb += swz<(4 << 10) | 0x1f>(pb);
    pa += swz<(8 << 10) | 0x1f>(pa);  pb += swz<(8 << 10) | 0x1f>(pb);
    if (k == 0) {
        float b0 = lin_b[0];
        out[bA] = pa + b0;
        out[bB] = pb + b0;
    }
}

extern "C" void kernel_launch(void* const* d_in, const int* in_sizes, int n_in,
                              void* d_out, int out_size, void* d_ws, size_t ws_size,
                              hipStream_t stream) {
    const float* x        = (const float*)d_in[0];
    const float* w_ih_mu  = (const float*)d_in[1];
    const float* w_ih_rho = (const float*)d_in[2];
    const float* w_hh_mu  = (const float*)d_in[3];
    const float* w_hh_rho = (const float*)d_in[4];
    const float* b_mu     = (const float*)d_in[5];
    const float* b_rho    = (const float*)d_in[6];
    const float* eps_ih   = (const float*)d_in[7];
    const float* eps_hh   = (const float*)d_in[8];
    const float* eps_b    = (const float*)d_in[9];
    const float* lin_w    = (const float*)d_in[10];
    const float* lin_b    = (const float*)d_in[11];
    float* out = (float*)d_out;

    const int n_b = in_sizes[0] / T_LEN;     // 8192
    dim3 grid(n_b / 32), block(256);         // 16 slots x 2 elements per block
    hipLaunchKernelGGL(bayes_lstm_kernel, grid, block, 0, stream,
                       x, w_ih_mu, w_ih_rho, w_hh_mu, w_hh_rho, b_mu, b_rho,
                       eps_ih, eps_hh, eps_b, lin_w, lin_b, out);
}